// Round 4
// baseline (249.372 us; speedup 1.0000x reference)
//
#include <hip/hip_runtime.h>

// Multibin binary conv:  y = conv2d(sign(x), sum_m sign(W_m), SAME) + sum_m b_m
// x: [16,256,256,32] f32   W: [4,3,3,32,32] f32   b: [4,32] f32 -> out f32
//
// Implicit GEMM, mfma_i32_32x32x32_i8 (exact: signs ±1 i8, wsum {-4..4} i8).
// 1-wave blocks (64 thr), 32-col x 8-row strip, grid 4096.  NO barriers.
// Rows staged ASYNC via global_load_lds (raw f32 ring of 3), packed LDS->LDS
// to i8 im2col (ring of 4), depth-2 pipeline with counted vmcnt waits.
//
// Round-4 change (single A/B vs round 3): REGULAR stores instead of
// nontemporal.  Theory: 3 different schedules all pinned at ~2.5 TB/s; the
// shared invariant is 1.5 TB/s of nt-writes draining synchronously at
// DRAM latency through a depth-limited write queue (~32 lines x 128B /
// ~2000cy ~= 2 B/cy/CU ~= the observed plateau).  Cached stores complete
// into L2 and drain via decoupled victim writebacks.  Ledger unchanged.

#define RH      8
#define PITCHB  48                    // packed bytes per pixel (32 ci + 16 pad)
#define PSLOT   (34 * PITCHB)         // 1632 B packed row slot (x4)
#define RSLOT   4096                  // raw slot: 32 interior px * 128 B (x3)
#define RAWOFF  (4 * PSLOT)           // packed [0,6528) raw [6528,18816)

typedef __attribute__((ext_vector_type(4)))  int i32x4;
typedef __attribute__((ext_vector_type(16))) int i32x16;

__device__ __forceinline__ void gload16(const void* g, void* l) {
    __builtin_amdgcn_global_load_lds(
        (const __attribute__((address_space(1))) void*)g,
        (__attribute__((address_space(3))) void*)l, 16, 0, 0);
}

__device__ __forceinline__ unsigned packsgn4(uint4 v) {
    unsigned r;
    r  =  (__uint_as_float(v.x) >= 0.0f) ? 0x01u : 0xFFu;
    r |= ((__uint_as_float(v.y) >= 0.0f) ? 0x01u : 0xFFu) << 8;
    r |= ((__uint_as_float(v.z) >= 0.0f) ? 0x01u : 0xFFu) << 16;
    r |= ((__uint_as_float(v.w) >= 0.0f) ? 0x01u : 0xFFu) << 24;
    return r;
}

// ---------------- prep: wsT[co][288] i8 + bsum[32] f32 into d_ws ----------------
__global__ void prep_kernel(const float* __restrict__ W, const float* __restrict__ bias,
                            signed char* __restrict__ wsT, float* __restrict__ bsum) {
    int t = blockIdx.x * 256 + threadIdx.x;
    if (t < 9216) {
        int k   = t >> 5;          // 0..287 = tap*32 + ci
        int co  = t & 31;
        int tap = k >> 5;
        int ci  = k & 31;
        float s = 0.0f;
        #pragma unroll
        for (int m = 0; m < 4; ++m) {
            float w = W[(m * 9 + tap) * 1024 + ci * 32 + co];
            s += (w >= 0.0f) ? 1.0f : -1.0f;
        }
        wsT[co * 288 + k] = (signed char)(int)s;
    }
    if (t < 32) {
        float s = 0.0f;
        #pragma unroll
        for (int m = 0; m < 4; ++m) s += bias[m * 32 + t];
        bsum[t] = s;
    }
}

// counted wait + scheduling fence
#define WAITV(N)                                                                \
    do {                                                                        \
        asm volatile("s_waitcnt vmcnt(" #N ")" ::: "memory");                   \
        __builtin_amdgcn_sched_barrier(0);                                      \
    } while (0)

// halo register select by row index (ring of 3, compile-time)
#define HSEL(J) ((((J) % 3) == 0) ? h0 : ((((J) % 3) == 1) ? h1 : h2))

// issue one row's staging: 4x global_load_lds (interior, swizzled source) +
// 1 per-lane halo dword (issued LAST -> its auto-wait covers the DMA too).
// 5 VMEM ops exactly.  sched_barrier pins the group in program order.
#define ISSUE_ROW(J, HREG)                                                      \
    do {                                                                        \
        const int row_  = r0 - 1 + (J);                                         \
        const int rowc_ = row_ < 0 ? 0 : (row_ > 255 ? 255 : row_);             \
        const char* gb_ = (const char*)(x + (long)((bimg * 256 + rowc_) * 256   \
                                                   + c0) * 32);                 \
        unsigned char* lb_ = lds + RAWOFF + ((J) % 3) * RSLOT;                  \
        _Pragma("unroll")                                                       \
        for (int k_ = 0; k_ < 4; ++k_)                                          \
            gload16(gb_ + k_ * 1024 + lswz16, lb_ + k_ * 1024);                 \
        HREG = *(x + (long)(bimg * 256 + rowc_) * 8192 + hoff);                 \
        __builtin_amdgcn_sched_barrier(0);                                      \
    } while (0)

// pack row J (raw f32 LDS -> signed i8 im2col LDS).  Halo byte FIRST
// (forces compiler's counted vmcnt for HREG, which retires the older DMA).
#define PACK_ROW(J, HREG)                                                       \
    do {                                                                        \
        const int row_   = r0 - 1 + (J);                                        \
        const bool rowok_ = (row_ >= 0) && (row_ < 256);                        \
        unsigned char* ps_ = lds + ((J) & 3) * PSLOT;                           \
        const unsigned char* rs_ = lds + RAWOFF + ((J) % 3) * RSLOT;            \
        ps_[hpx * PITCHB + (lane & 31)] =                                       \
            (rowok_ && hok) ? ((HREG >= 0.0f) ? 0x01 : 0xFF) : 0;               \
        uint4 o_;                                                               \
        if (rowok_) {                                                           \
            uint4 w0_ = *(const uint4*)(rs_ + (ppx * 8 + ((ph * 4 + 0) ^ pxr)) * 16); \
            uint4 w1_ = *(const uint4*)(rs_ + (ppx * 8 + ((ph * 4 + 1) ^ pxr)) * 16); \
            uint4 w2_ = *(const uint4*)(rs_ + (ppx * 8 + ((ph * 4 + 2) ^ pxr)) * 16); \
            uint4 w3_ = *(const uint4*)(rs_ + (ppx * 8 + ((ph * 4 + 3) ^ pxr)) * 16); \
            o_ = make_uint4(packsgn4(w0_), packsgn4(w1_),                       \
                            packsgn4(w2_), packsgn4(w3_));                      \
        } else {                                                                \
            o_ = make_uint4(0u, 0u, 0u, 0u);                                    \
        }                                                                       \
        *(uint4*)(ps_ + (ppx + 1) * PITCHB + ph * 16) = o_;                     \
    } while (0)

__global__ __launch_bounds__(64, 2) void conv_kernel(const float* __restrict__ x,
                                                     const signed char* __restrict__ wsT,
                                                     const float* __restrict__ bsum,
                                                     float* __restrict__ out) {
    __shared__ __align__(16) unsigned char lds[4 * PSLOT + 3 * RSLOT];  // 18816 B

    const int lane = threadIdx.x;     // single wave per block
    const int lrow = lane & 31;       // A: pixel row / B,D: cout column
    const int lk   = lane >> 5;       // K-half selector

    const int bs   = blockIdx.x;      // 4096 = 16 img x 32 rowstrips x 8 colstrips
    const int c0   = (bs & 7) * 32;
    const int r0   = ((bs >> 3) & 31) * RH;
    const int bimg = bs >> 8;

    // B fragments + bias first: their 10 VMEM ops retire under prologue waits
    i32x4 bfrag[9];
    #pragma unroll
    for (int t = 0; t < 9; ++t)
        bfrag[t] = *(const i32x4*)(wsT + lrow * 288 + t * 32 + lk * 16);
    const float bsv = bsum[lrow];

    // geometry
    const int lswz16 = (lane ^ ((lane >> 3) & 7)) * 16;   // global-side pre-swizzle
    const int hcol   = (lane < 32) ? (c0 > 0 ? c0 - 1 : 0)
                                   : (c0 + 32 < 256 ? c0 + 32 : 255);
    const bool hok   = (lane < 32) ? (c0 > 0) : (c0 + 32 < 256);
    const int  hpx   = (lane < 32) ? 0 : 33;
    const long hoff  = (long)hcol * 32 + (lane & 31);     // in floats
    const int  ppx   = lane >> 1;                         // pack: pixel 0..31
    const int  ph    = lane & 1;                          // pack: ci half
    const int  pxr   = ppx & 7;                           // raw read de-swizzle

    float h0 = 0.f, h1 = 0.f, h2 = 0.f;

    // ---- prologue: rows j0..j2 async, packed under counted waits ----
    ISSUE_ROW(0, HSEL(0));
    ISSUE_ROW(1, HSEL(1));
    ISSUE_ROW(2, HSEL(2));
    WAITV(10);  PACK_ROW(0, HSEL(0));
    WAITV(5);   PACK_ROW(1, HSEL(1));
    ISSUE_ROW(3, HSEL(3));
    WAITV(5);   PACK_ROW(2, HSEL(2));

    const int a_off = lrow * PITCHB + lk * 16;

    #pragma unroll
    for (int i = 0; i < RH; ++i) {
        // issue row j=i+4 (rows j0..j9 total)
        if (i <= RH - 3) ISSUE_ROW(i + 4, HSEL(i + 4));

        // wait for row j=i+3's DMA (one full iteration old); stores + fresh
        // loads stay outstanding.  Ledger (group order pinned by sched_barriers):
        //   i=0: [j4:5] -> 5    i=1..5: [stores:16][j:5] -> 21    i=6: [stores:16] -> 16
        if (i == 0)      { WAITV(5);  }
        else if (i == 1) { WAITV(21); }
        else if (i == 2) { WAITV(21); }
        else if (i == 3) { WAITV(21); }
        else if (i == 4) { WAITV(21); }
        else if (i == 5) { WAITV(21); }
        else if (i == 6) { WAITV(16); }
        if (i <= RH - 2) PACK_ROW(i + 3, HSEL(i + 3));

        // ---- MFMA: output row r0+i from packed slots (i, i+1, i+2) & 3 ----
        i32x16 acc = {};
        #pragma unroll
        for (int dh = 0; dh < 3; ++dh) {
            const unsigned char* sb = lds + ((i + dh) & 3) * PSLOT + a_off;
            #pragma unroll
            for (int dw = 0; dw < 3; ++dw) {
                i32x4 a = *(const i32x4*)(sb + dw * PITCHB);
                acc = __builtin_amdgcn_mfma_i32_32x32x32_i8(a, bfrag[dh * 3 + dw],
                                                            acc, 0, 0, 0);
            }
        }

        // ---- store (REGULAR, cached): D col = lrow, row = (reg&3)+8*(reg>>2)+4*lk ----
        float* op = out + ((long)((bimg * 256 + (r0 + i)) * 256 + c0)) * 32 + lrow;
        #pragma unroll
        for (int reg = 0; reg < 16; ++reg) {
            int pr = (reg & 3) + 8 * (reg >> 2) + 4 * lk;
            op[pr * 32] = (float)acc[reg] + bsv;
        }
    }
}

extern "C" void kernel_launch(void* const* d_in, const int* in_sizes, int n_in,
                              void* d_out, int out_size, void* d_ws, size_t ws_size,
                              hipStream_t stream) {
    const float* x    = (const float*)d_in[0];   // [16,256,256,32]
    const float* W    = (const float*)d_in[1];   // [4,3,3,32,32]
    const float* bias = (const float*)d_in[2];   // [4,32]
    float* out = (float*)d_out;

    signed char* wsT = (signed char*)d_ws;              // 9216 B
    float* bsum = (float*)((char*)d_ws + 9216);         // 32 f32

    prep_kernel<<<36, 256, 0, stream>>>(W, bias, wsT, bsum);
    conv_kernel<<<4096, 64, 0, stream>>>(x, wsT, bsum, out);
}

// Round 5
// 247.679 us; speedup vs baseline: 1.0068x; 1.0068x over previous
//
#include <hip/hip_runtime.h>

// Multibin binary conv:  y = conv2d(sign(x), sum_m sign(W_m), SAME) + sum_m b_m
// x: [16,256,256,32] f32   W: [4,3,3,32,32] f32   b: [4,32] f32 -> out f32
//
// Implicit GEMM, mfma_i32_32x32x32_i8 (exact: signs ±1 i8, wsum {-4..4} i8).
// 1-wave blocks (64 thr), 32-col x 8-row strip, grid 4096.  NO barriers.
//
// Round-5: occupancy x depth.  Rows staged in REGISTERS (interior 4x float4
// + 1 halo dword = 17 VGPR/row, two named A/B buffers, all static refs),
// packed+committed to the 4-slot i8 im2col LDS ring one full iteration
// after issue (compiler emits counted vmcnt(21): 16 stores + 5 fresh loads
// stay outstanding).  LDS = 6.5 KB only -> 16 blocks/CU resident
// (4 waves/SIMD, pinned via amdgpu_waves_per_eu(4,4) so the allocator
// budgets 128 VGPRs and cannot spill-squeeze like round 2).
// In-flight reads/CU ~ 16 waves x 4.3 KB ~ 69 KB, ~3x any prior round.

#define RH      8
#define PITCHB  48                    // packed bytes per pixel (32 ci + 16 pad)
#define PSLOT   (34 * PITCHB)         // 1632 B packed row slot; 4 slots = 6528 B

typedef __attribute__((ext_vector_type(4)))  int i32x4;
typedef __attribute__((ext_vector_type(16))) int i32x16;

__device__ __forceinline__ unsigned packsgn4f(float4 v) {
    unsigned r;
    r  =  ((v.x >= 0.0f) ? 0x01u : 0xFFu);
    r |= ((v.y >= 0.0f) ? 0x01u : 0xFFu) << 8;
    r |= ((v.z >= 0.0f) ? 0x01u : 0xFFu) << 16;
    r |= ((v.w >= 0.0f) ? 0x01u : 0xFFu) << 24;
    return r;
}

// ---------------- prep: wsT[co][288] i8 + bsum[32] f32 into d_ws ----------------
__global__ void prep_kernel(const float* __restrict__ W, const float* __restrict__ bias,
                            signed char* __restrict__ wsT, float* __restrict__ bsum) {
    int t = blockIdx.x * 256 + threadIdx.x;
    if (t < 9216) {
        int k   = t >> 5;          // 0..287 = tap*32 + ci
        int co  = t & 31;
        int tap = k >> 5;
        int ci  = k & 31;
        float s = 0.0f;
        #pragma unroll
        for (int m = 0; m < 4; ++m) {
            float w = W[(m * 9 + tap) * 1024 + ci * 32 + co];
            s += (w >= 0.0f) ? 1.0f : -1.0f;
        }
        wsT[co * 288 + k] = (signed char)(int)s;
    }
    if (t < 32) {
        float s = 0.0f;
        #pragma unroll
        for (int m = 0; m < 4; ++m) s += bias[m * 32 + t];
        bsum[t] = s;
    }
}

// issue one row into named regs: 4 interior float4 (always-valid cols) +
// 1 halo dword.  Row clamped (validity applied at commit).  5 VMEM ops.
#define ISSUE(J, V0, V1, V2, V3, VH)                                            \
    do {                                                                        \
        const int row_  = r0 - 1 + (J);                                         \
        const int rowc_ = row_ < 0 ? 0 : (row_ > 255 ? 255 : row_);             \
        const char* rb_ = (const char*)(x + ((long)(bimg * 256 + rowc_) * 256   \
                                             + c0) * 32);                       \
        V0 = *(const float4*)(rb_ + goff0);                                     \
        V1 = *(const float4*)(rb_ + goff1);                                     \
        V2 = *(const float4*)(rb_ + goff2);                                     \
        V3 = *(const float4*)(rb_ + goff3);                                     \
        VH = *(x + (long)(bimg * 256 + rowc_) * 8192 + hbase);                  \
        __builtin_amdgcn_sched_barrier(0);                                      \
    } while (0)

// pack + commit one row to im2col slot (J&3).  Compiler's register deps on
// V* emit the counted vmcnt (loads are the oldest outstanding group).
#define COMMIT(J, V0, V1, V2, V3, VH)                                           \
    do {                                                                        \
        const int row_   = r0 - 1 + (J);                                        \
        const bool rowok_ = (row_ >= 0) && (row_ < 256);                        \
        unsigned char* ps_ = lds + ((J) & 3) * PSLOT;                           \
        ps_[hpx * PITCHB + (lane & 31)] =                                       \
            (rowok_ && hok) ? ((VH >= 0.0f) ? 0x01 : 0xFF) : 0;                 \
        *(unsigned*)(ps_ + woff0) = rowok_ ? packsgn4f(V0) : 0u;                \
        *(unsigned*)(ps_ + woff1) = rowok_ ? packsgn4f(V1) : 0u;                \
        *(unsigned*)(ps_ + woff2) = rowok_ ? packsgn4f(V2) : 0u;                \
        *(unsigned*)(ps_ + woff3) = rowok_ ? packsgn4f(V3) : 0u;                \
    } while (0)

// MFMA over slots (I, I+1, I+2) & 3, then cached stores of output row r0+I
#define MFMA_STORE(I)                                                           \
    do {                                                                        \
        i32x16 acc = {};                                                        \
        _Pragma("unroll")                                                       \
        for (int dh = 0; dh < 3; ++dh) {                                        \
            const unsigned char* sb = lds + (((I) + dh) & 3) * PSLOT + a_off;   \
            _Pragma("unroll")                                                   \
            for (int dw = 0; dw < 3; ++dw) {                                    \
                i32x4 a = *(const i32x4*)(sb + dw * PITCHB);                    \
                acc = __builtin_amdgcn_mfma_i32_32x32x32_i8(                    \
                          a, bfrag[dh * 3 + dw], acc, 0, 0, 0);                 \
            }                                                                   \
        }                                                                       \
        float* op = out + ((long)((bimg * 256 + (r0 + (I))) * 256 + c0)) * 32   \
                    + lrow;                                                     \
        _Pragma("unroll")                                                       \
        for (int reg = 0; reg < 16; ++reg) {                                    \
            int pr = (reg & 3) + 8 * (reg >> 2) + 4 * lk;                       \
            op[pr * 32] = (float)acc[reg] + bsv;                                \
        }                                                                       \
    } while (0)

__global__ __launch_bounds__(64, 4) __attribute__((amdgpu_waves_per_eu(4, 4)))
void conv_kernel(const float* __restrict__ x,
                 const signed char* __restrict__ wsT,
                 const float* __restrict__ bsum,
                 float* __restrict__ out) {
    __shared__ __align__(16) unsigned char lds[4 * PSLOT];   // 6528 B

    const int lane = threadIdx.x;     // single wave per block
    const int lrow = lane & 31;       // A: pixel row / B,D: cout column
    const int lk   = lane >> 5;       // K-half selector

    const int bs   = blockIdx.x;      // 4096 = 16 img x 32 rowstrips x 8 colstrips
    const int c0   = (bs & 7) * 32;
    const int r0   = ((bs >> 3) & 31) * RH;
    const int bimg = bs >> 8;

    // per-lane static geometry: interior unit f = lane + p*64 over 32px x 8 chunks
    int goff0, goff1, goff2, goff3, woff0, woff1, woff2, woff3;
    {
        int f, pix, ch;
        f = lane;        pix = f >> 3; ch = f & 7;
        goff0 = pix * 128 + ch * 16;  woff0 = (pix + 1) * PITCHB + ch * 4;
        f = lane + 64;   pix = f >> 3; ch = f & 7;
        goff1 = pix * 128 + ch * 16;  woff1 = (pix + 1) * PITCHB + ch * 4;
        f = lane + 128;  pix = f >> 3; ch = f & 7;
        goff2 = pix * 128 + ch * 16;  woff2 = (pix + 1) * PITCHB + ch * 4;
        f = lane + 192;  pix = f >> 3; ch = f & 7;
        goff3 = pix * 128 + ch * 16;  woff3 = (pix + 1) * PITCHB + ch * 4;
    }
    // halo: lanes 0-31 -> px0 (col c0-1), lanes 32-63 -> px33 (col c0+32)
    const int  hcol = (lane < 32) ? (c0 > 0 ? c0 - 1 : 0)
                                  : (c0 + 32 < 256 ? c0 + 32 : 255);
    const bool hok  = (lane < 32) ? (c0 > 0) : (c0 + 32 < 256);
    const int  hpx  = (lane < 32) ? 0 : 33;
    const int  hbase = hcol * 32 + (lane & 31);           // floats within row

    // B fragments (10 VMEM, retire under prologue waits)
    i32x4 bfrag[9];
    #pragma unroll
    for (int t = 0; t < 9; ++t)
        bfrag[t] = *(const i32x4*)(wsT + lrow * 288 + t * 32 + lk * 16);
    const float bsv = bsum[lrow];

    // two named row buffers
    float4 A0, A1, A2, A3;  float Ah;
    float4 B0, B1, B2, B3;  float Bh;

    // ---- prologue: rows J0..J2 committed, J3 in flight (in B) ----
    ISSUE(0, A0, A1, A2, A3, Ah);
    ISSUE(1, B0, B1, B2, B3, Bh);
    COMMIT(0, A0, A1, A2, A3, Ah);     // waits vmcnt<=5 (J1 outstanding)
    ISSUE(2, A0, A1, A2, A3, Ah);
    COMMIT(1, B0, B1, B2, B3, Bh);     // waits vmcnt<=5 (J2)
    ISSUE(3, B0, B1, B2, B3, Bh);
    COMMIT(2, A0, A1, A2, A3, Ah);     // waits vmcnt<=5 (J3)

    const int a_off = lrow * PITCHB + lk * 16;

    // ---- steady state: iter i issues J=i+4, commits J=i+3 (1 iter old) ----
    ISSUE(4, A0, A1, A2, A3, Ah);  COMMIT(3, B0, B1, B2, B3, Bh);  MFMA_STORE(0);
    ISSUE(5, B0, B1, B2, B3, Bh);  COMMIT(4, A0, A1, A2, A3, Ah);  MFMA_STORE(1);
    ISSUE(6, A0, A1, A2, A3, Ah);  COMMIT(5, B0, B1, B2, B3, Bh);  MFMA_STORE(2);
    ISSUE(7, B0, B1, B2, B3, Bh);  COMMIT(6, A0, A1, A2, A3, Ah);  MFMA_STORE(3);
    ISSUE(8, A0, A1, A2, A3, Ah);  COMMIT(7, B0, B1, B2, B3, Bh);  MFMA_STORE(4);
    ISSUE(9, B0, B1, B2, B3, Bh);  COMMIT(8, A0, A1, A2, A3, Ah);  MFMA_STORE(5);
    COMMIT(9, B0, B1, B2, B3, Bh);                                 MFMA_STORE(6);
    MFMA_STORE(7);
}

extern "C" void kernel_launch(void* const* d_in, const int* in_sizes, int n_in,
                              void* d_out, int out_size, void* d_ws, size_t ws_size,
                              hipStream_t stream) {
    const float* x    = (const float*)d_in[0];   // [16,256,256,32]
    const float* W    = (const float*)d_in[1];   // [4,3,3,32,32]
    const float* bias = (const float*)d_in[2];   // [4,32]
    float* out = (float*)d_out;

    signed char* wsT = (signed char*)d_ws;              // 9216 B
    float* bsum = (float*)((char*)d_ws + 9216);         // 32 f32

    prep_kernel<<<36, 256, 0, stream>>>(W, bias, wsT, bsum);
    conv_kernel<<<4096, 64, 0, stream>>>(x, wsT, bsum, out);
}